// Round 1
// baseline (1463.701 us; speedup 1.0000x reference)
//
#include <hip/hip_runtime.h>
#include <stdint.h>

// Problem constants
#define BTOT     65536
#define IN_DIM   1024
#define NUM_PROD 2048
#define OUT_DIM  2048

typedef unsigned short u16;
typedef __attribute__((ext_vector_type(8))) short          bf16x8;   // 8 bf16 (4 VGPRs) MFMA A/B frag
typedef __attribute__((ext_vector_type(8))) unsigned short ushort8;
typedef __attribute__((ext_vector_type(4))) float          f32x4;    // MFMA C/D frag

// round-to-nearest-even fp32 -> bf16 (bit pattern)
__device__ __forceinline__ u16 f2bf(float f) {
    uint32_t u = __float_as_uint(f);
    u = (u + 0x7fff + ((u >> 16) & 1)) >> 16;
    return (u16)u;
}

// async global->LDS, 16B per lane; LDS dest = wave-uniform base + lane*16
__device__ __forceinline__ void load_lds16(const void* g, void* l) {
    __builtin_amdgcn_global_load_lds((const __attribute__((address_space(1))) void*)g,
                                     (__attribute__((address_space(3))) void*)l,
                                     16, 0, 0);
}

// ---------------------------------------------------------------------------
// Kernel 1: W_prod (fp32 [OUT_DIM][NUM_PROD]) -> bf16 bits
// ---------------------------------------------------------------------------
__global__ __launch_bounds__(256) void cast_w_kernel(const float* __restrict__ W,
                                                     u16* __restrict__ Wb) {
    int i = blockIdx.x * 256 + threadIdx.x;          // group of 8 floats
    const float4* wp = (const float4*)W;
    float4 a = wp[2 * i];
    float4 b = wp[2 * i + 1];
    ushort8 o;
    o[0] = f2bf(a.x); o[1] = f2bf(a.y); o[2] = f2bf(a.z); o[3] = f2bf(a.w);
    o[4] = f2bf(b.x); o[5] = f2bf(b.y); o[6] = f2bf(b.z); o[7] = f2bf(b.w);
    *(ushort8*)(Wb + (size_t)i * 8) = o;
}

// ---------------------------------------------------------------------------
// Kernel 2: Q[b][p] = bf16( x[b][i_p] * x[b][j_p] )
// One x-row staged in LDS per iteration; idx pairs cached in registers.
// ---------------------------------------------------------------------------
#define ROWS_PER_BLOCK 32

__global__ __launch_bounds__(256) void quad_kernel(const float* __restrict__ x,
                                                   const int*   __restrict__ idx,
                                                   u16*         __restrict__ Q,
                                                   int rowBase) {
    __shared__ float xs[IN_DIM];
    const int t = threadIdx.x;

    int2 pr[8];
    const int2* ip = (const int2*)idx;
#pragma unroll
    for (int j = 0; j < 8; ++j) pr[j] = ip[t * 8 + j];

    const int r0 = blockIdx.x * ROWS_PER_BLOCK;
    for (int r = 0; r < ROWS_PER_BLOCK; ++r) {
        const size_t b = (size_t)rowBase + r0 + r;
        __syncthreads();
        ((float4*)xs)[t] = ((const float4*)(x + b * IN_DIM))[t];   // 256*16B = 4KB row
        __syncthreads();
        ushort8 o;
#pragma unroll
        for (int j = 0; j < 8; ++j)
            o[j] = f2bf(xs[pr[j].x] * xs[pr[j].y]);
        *(ushort8*)(Q + (size_t)(r0 + r) * NUM_PROD + t * 8) = o;
    }
}

// ---------------------------------------------------------------------------
// Kernel 3: C[Mc][OUT_DIM] (fp32) = A[Mc][K] (bf16) * B[OUT_DIM][K]^T (bf16)
// m97 structure: 128x128 tile, BK=64, 4 waves * 4x4 of 16x16x32 bf16 MFMA,
// global_load_lds width=16 staging, XOR chunk swizzle (on the global source
// address, so the wave-uniform LDS base constraint holds).
// ---------------------------------------------------------------------------
__global__ __launch_bounds__(256) void gemm_bt(const u16* __restrict__ A,
                                               const u16* __restrict__ Bm,
                                               float*     __restrict__ C) {
    __shared__ __align__(16) u16 As[128 * 64];
    __shared__ __align__(16) u16 Bs[128 * 64];

    const int tid  = threadIdx.x;
    const int lane = tid & 63;
    const int wave = tid >> 6;

    const int rowBaseA = blockIdx.y * 128;   // M tile
    const int colBaseB = blockIdx.x * 128;   // N tile

    const int wm = (wave >> 1) * 64;         // wave's 64x64 sub-tile
    const int wn = (wave & 1) * 64;
    const int q  = lane >> 4;                // quad 0..3
    const int lr = lane & 15;

    f32x4 acc[4][4] = {};

    for (int k0 = 0; k0 < NUM_PROD; k0 += 64) {
        __syncthreads();  // previous iter's LDS reads done before overwrite
#pragma unroll
        for (int i = 0; i < 4; ++i) {
            const int physChunkBase = (wave * 4 + i) * 64;          // wave-uniform
            const int physChunk = physChunkBase + lane;
            const int physRow   = physChunk >> 3;
            const int physCol   = physChunk & 7;
            const int srcChunk  = physCol ^ (physRow & 7);          // XOR swizzle
            load_lds16(A  + (size_t)(rowBaseA + physRow) * NUM_PROD + k0 + srcChunk * 8,
                       &As[physChunkBase * 8]);
            load_lds16(Bm + (size_t)(colBaseB + physRow) * NUM_PROD + k0 + srcChunk * 8,
                       &Bs[physChunkBase * 8]);
        }
        __syncthreads();  // compiler emits vmcnt(0) drain here

#pragma unroll
        for (int ks = 0; ks < 2; ++ks) {
            bf16x8 af[4], bfr[4];
            const int c = ks * 4 + q;                 // logical 8-elem chunk in K
#pragma unroll
            for (int mt = 0; mt < 4; ++mt) {
                const int row = wm + mt * 16 + lr;
                af[mt] = *(const bf16x8*)&As[row * 64 + (c ^ (row & 7)) * 8];
            }
#pragma unroll
            for (int nt = 0; nt < 4; ++nt) {
                const int row = wn + nt * 16 + lr;
                bfr[nt] = *(const bf16x8*)&Bs[row * 64 + (c ^ (row & 7)) * 8];
            }
#pragma unroll
            for (int mt = 0; mt < 4; ++mt)
#pragma unroll
                for (int nt = 0; nt < 4; ++nt)
                    acc[mt][nt] = __builtin_amdgcn_mfma_f32_16x16x32_bf16(
                        af[mt], bfr[nt], acc[mt][nt], 0, 0, 0);
        }
    }

    // Epilogue: C/D layout col = lane&15, row = quad*4 + reg   [m89/m91]
#pragma unroll
    for (int mt = 0; mt < 4; ++mt) {
#pragma unroll
        for (int nt = 0; nt < 4; ++nt) {
            const int col   = colBaseB + wn + nt * 16 + lr;
            const int rbase = rowBaseA + wm + mt * 16 + q * 4;
            float* cp = C + (size_t)rbase * OUT_DIM + col;
#pragma unroll
            for (int r = 0; r < 4; ++r)
                cp[(size_t)r * OUT_DIM] = acc[mt][nt][r];
        }
    }
}

// ---------------------------------------------------------------------------
extern "C" void kernel_launch(void* const* d_in, const int* in_sizes, int n_in,
                              void* d_out, int out_size, void* d_ws, size_t ws_size,
                              hipStream_t stream) {
    const float* x   = (const float*)d_in[0];
    const int*   idx = (const int*)d_in[1];
    const float* W   = (const float*)d_in[2];
    float*       out = (float*)d_out;

    const size_t wb_bytes = (size_t)OUT_DIM * NUM_PROD * 2;   // 8 MB bf16 W
    u16* Wb = (u16*)d_ws;
    u16* Q  = (u16*)((char*)d_ws + wb_bytes);

    // Pick largest B-chunk whose bf16 Q buffer fits in the workspace.
    const size_t qcap = (ws_size > wb_bytes) ? (ws_size - wb_bytes) : 0;
    int rows = BTOT;
    while (rows > 128 && (size_t)rows * NUM_PROD * 2 > qcap) rows >>= 1;

    cast_w_kernel<<<(OUT_DIM * NUM_PROD) / (256 * 8), 256, 0, stream>>>(W, Wb);

    for (int base = 0; base < BTOT; base += rows) {
        quad_kernel<<<rows / ROWS_PER_BLOCK, 256, 0, stream>>>(x, idx, Q, base);
        dim3 g(OUT_DIM / 128, rows / 128);
        gemm_bt<<<g, dim3(256), 0, stream>>>(Q, Wb, out + (size_t)base * OUT_DIM);
    }
}